// Round 3
// baseline (6961.049 us; speedup 1.0000x reference)
//
#include <hip/hip_runtime.h>
#include <hip/hip_bf16.h>
#include <stdint.h>

// 2-layer LSTM, B=1024 T=80 E=100 U=512, bf16 MFMA.
// R3: ONE persistent cooperative kernel runs all 81 pipelined phases
// (layer2(t-1) || layer1(t)) with a custom device-scope grid barrier.
// c-state in registers for the whole run; in-register gate epilogue (wave spans
// all 4 gates -> i,f,g,o of a (row,unit) are in the same lane); A frags direct
// global->VGPR prefetch; B weights via global_load_lds double-buffer.

#define T_ 80

using bf16 = __hip_bfloat16;
typedef __attribute__((ext_vector_type(8))) short short8;
typedef __attribute__((ext_vector_type(4))) float f32x4;

__device__ __forceinline__ float sigf(float x) { return 1.f / (1.f + __expf(-x)); }
__device__ __forceinline__ float tanh_f(float x) { return 2.f / (1.f + __expf(-2.f * x)) - 1.f; }

typedef const __attribute__((address_space(1))) void* gp1_t;
typedef __attribute__((address_space(3))) void* lp3_t;
__device__ __forceinline__ void llds16(const void* g, void* l) {
  // HW writes lane i's 16B at (wave-uniform) l + i*16
  __builtin_amdgcn_global_load_lds((gp1_t)g, (lp3_t)l, 16, 0, 0);
}

// XP[t][b][e] (e padded to 128), bf16
__global__ void embed_kernel(const int* __restrict__ tokens, const float* __restrict__ emb,
                             bf16* __restrict__ XP) {
  int idx = blockIdx.x * 256 + threadIdx.x;
  int e = idx & 127;
  int bt = idx >> 7;
  int b = bt & 1023;
  int t = bt >> 10;
  if (t >= T_) return;
  int tok = tokens[b * T_ + t];
  float v = (e < 100) ? emb[tok * 100 + e] : 0.f;
  XP[idx] = __float2bfloat16(v);
}

// W [Kreal][2048] fp32 -> WT [2048][Kp] bf16 via LDS tile (coalesced both ways)
__global__ void transpose_kernel(const float* __restrict__ W, bf16* __restrict__ WT,
                                 int Kreal, int Kp) {
  __shared__ float tile[32][33];
  int tn = blockIdx.x * 32;
  int tk = blockIdx.y * 32;
  int lx = threadIdx.x & 31;
  int ly = threadIdx.x >> 5;
#pragma unroll
  for (int r = ly; r < 32; r += 8) {
    int k = tk + r;
    tile[r][lx] = (k < Kreal) ? W[(size_t)k * 2048 + tn + lx] : 0.f;
  }
  __syncthreads();
#pragma unroll
  for (int r = ly; r < 32; r += 8)
    WT[(size_t)(tn + r) * Kp + tk + lx] = __float2bfloat16(tile[lx][r]);
}

struct PP {
  const bf16* XP;
  const bf16* W1T; const bf16* U1T; const bf16* W2T; const bf16* U2T;
  const float* b1; const float* b2;
  bf16* H1; bf16* H2;   // 2 ping-pong buffers each, stride 524288 elems
  unsigned* bar;        // [0]=count, [32]=generation
};

// 512 blocks x 256 thr (2/CU). Block: 128 rows x 16 units (64 z-cols).
// Wave w: rows +w*32..+32, all 64 cols. Role: bid>>8 (1=layer1, 0=layer2).
__global__ __launch_bounds__(256, 2) void lstm_persistent(PP P) {
  __shared__ alignas(16) char sB[8192];  // 2 x 4KB B-tile staging
  const int bid = blockIdx.x;
  const int half = bid >> 8;             // 1: layer1, 0: layer2
  const int xcd = bid & 7;
  const int j = (bid >> 3) & 31;
  const int un = (j & 15) | ((xcd & 1) << 4);   // XCD swizzle: un-half + bm-pair per XCD
  const int bm = (j >> 4) | ((xcd >> 1) << 1);  // so weight slice ~3.4MB fits 4MB L2
  const int u0 = un * 16;
  const int tid = threadIdx.x;
  const int w = tid >> 6, l = tid & 63, q = l >> 4, m = l & 15;

  const int row0 = bm * 128 + w * 32 + m;   // A-frag row, group 0
  const int row1 = row0 + 16;               // group 1

  const bf16* Wt = half ? P.W1T : P.W2T;
  const bf16* Ut = half ? P.U1T : P.U2T;
  const float* bs = half ? P.b1 : P.b2;
  const int ldw = half ? 128 : 512;
  const int nkt0 = half ? 4 : 16;
  const int nkt = nkt0 + 16;

  const float bi = bs[0 * 512 + u0 + m];
  const float bfg = bs[1 * 512 + u0 + m];
  const float bg = bs[2 * 512 + u0 + m];
  const float bo = bs[3 * 512 + u0 + m];

  float creg[8] = {0, 0, 0, 0, 0, 0, 0, 0};  // cell state, [rg*4+r], whole run

  // B staging: wave w stages gate w's 16 n-rows (unit u0+m), lane lands q*256+m*16
  const bf16* wrow = Wt + (size_t)(w * 512 + u0 + m) * ldw + q * 8;
  const bf16* urow = Ut + (size_t)(w * 512 + u0 + m) * 512 + q * 8;
  char* sdst = sB + w * 1024;

  for (int phase = 0; phase <= T_; ++phase) {
    const int t = half ? phase : phase - 1;
    const bool active = half ? (phase < T_) : (phase >= 1);
    if (active) {
      const bf16* A0; int lda0; const bf16* A1; bf16* Hout;
      if (half) {  // layer1(t): [XP_t | H1[t&1]] -> H1[(t+1)&1]
        A0 = P.XP + (size_t)t * 131072; lda0 = 128;
        A1 = P.H1 + (size_t)(t & 1) * 524288;
        Hout = P.H1 + (size_t)((t + 1) & 1) * 524288;
      } else {     // layer2(t): [H1[(t+1)&1] | H2[t&1]] -> H2[(t+1)&1]
        A0 = P.H1 + (size_t)((t + 1) & 1) * 524288; lda0 = 512;
        A1 = P.H2 + (size_t)(t & 1) * 524288;
        Hout = P.H2 + (size_t)((t + 1) & 1) * 524288;
      }
      const bf16* pa00 = A0 + (size_t)row0 * lda0 + q * 8;
      const bf16* pa01 = A0 + (size_t)row1 * lda0 + q * 8;
      const bf16* pa10 = A1 + (size_t)row0 * 512 + q * 8;
      const bf16* pa11 = A1 + (size_t)row1 * 512 + q * 8;

      f32x4 acc[2][4];
#pragma unroll
      for (int i = 0; i < 2; ++i)
#pragma unroll
        for (int g = 0; g < 4; ++g) acc[i][g] = f32x4{0.f, 0.f, 0.f, 0.f};

      // prologue: stage tile 0, prefetch A(0)
      llds16(wrow, sdst);
      uint4 ap0 = *(const uint4*)pa00;
      uint4 ap1 = *(const uint4*)pa01;

      for (int kt = 0; kt < nkt; ++kt) {
        const int cb = (kt & 1) * 4096;
        __syncthreads();  // drains vmcnt: B(kt) in LDS, ap = A(kt)
        if (kt + 1 < nkt) {
          const int k1 = kt + 1;
          char* nd = sdst + (4096 - cb);
          if (k1 < nkt0) {
            llds16(wrow + k1 * 32, nd);
          } else {
            llds16(urow + (k1 - nkt0) * 32, nd);
          }
        }
        uint4 a0v = ap0, a1v = ap1;
        if (kt + 1 < nkt) {
          const int k1 = kt + 1;
          if (k1 < nkt0) {
            ap0 = *(const uint4*)(pa00 + k1 * 32);
            ap1 = *(const uint4*)(pa01 + k1 * 32);
          } else {
            const int kk = (k1 - nkt0) * 32;
            ap0 = *(const uint4*)(pa10 + kk);
            ap1 = *(const uint4*)(pa11 + kk);
          }
        }
        short8 bf0 = *(const short8*)(sB + cb + 0 * 1024 + q * 256 + m * 16);
        short8 bf1 = *(const short8*)(sB + cb + 1 * 1024 + q * 256 + m * 16);
        short8 bf2 = *(const short8*)(sB + cb + 2 * 1024 + q * 256 + m * 16);
        short8 bf3 = *(const short8*)(sB + cb + 3 * 1024 + q * 256 + m * 16);
        short8 a0 = *(short8*)&a0v;
        short8 a1 = *(short8*)&a1v;
        acc[0][0] = __builtin_amdgcn_mfma_f32_16x16x32_bf16(a0, bf0, acc[0][0], 0, 0, 0);
        acc[0][1] = __builtin_amdgcn_mfma_f32_16x16x32_bf16(a0, bf1, acc[0][1], 0, 0, 0);
        acc[0][2] = __builtin_amdgcn_mfma_f32_16x16x32_bf16(a0, bf2, acc[0][2], 0, 0, 0);
        acc[0][3] = __builtin_amdgcn_mfma_f32_16x16x32_bf16(a0, bf3, acc[0][3], 0, 0, 0);
        acc[1][0] = __builtin_amdgcn_mfma_f32_16x16x32_bf16(a1, bf0, acc[1][0], 0, 0, 0);
        acc[1][1] = __builtin_amdgcn_mfma_f32_16x16x32_bf16(a1, bf1, acc[1][1], 0, 0, 0);
        acc[1][2] = __builtin_amdgcn_mfma_f32_16x16x32_bf16(a1, bf2, acc[1][2], 0, 0, 0);
        acc[1][3] = __builtin_amdgcn_mfma_f32_16x16x32_bf16(a1, bf3, acc[1][3], 0, 0, 0);
      }

      // in-register epilogue: lane (q,m) holds rows q*4+r of each 16-row group,
      // col m of each gate group -> (row, unit u0+m) gates all local.
      const int rb = bm * 128 + w * 32 + q * 4;
#pragma unroll
      for (int rg = 0; rg < 2; ++rg)
#pragma unroll
        for (int r = 0; r < 4; ++r) {
          const int row = rb + rg * 16 + r;
          float zi = acc[rg][0][r] + bi;
          float zf = acc[rg][1][r] + bfg;
          float zg = acc[rg][2][r] + bg;
          float zo = acc[rg][3][r] + bo;
          float c = sigf(zf) * creg[rg * 4 + r] + sigf(zi) * tanh_f(zg);
          creg[rg * 4 + r] = c;
          Hout[(size_t)row * 512 + u0 + m] = __float2bfloat16(sigf(zo) * tanh_f(c));
        }
    }

    if (phase < T_) {  // grid barrier between phases
      __syncthreads();
      if (tid == 0) {
        __threadfence();
        unsigned g = __hip_atomic_load(P.bar + 32, __ATOMIC_RELAXED, __HIP_MEMORY_SCOPE_AGENT);
        unsigned a = __hip_atomic_fetch_add(P.bar, 1u, __ATOMIC_ACQ_REL, __HIP_MEMORY_SCOPE_AGENT);
        if (a == 511u) {
          __hip_atomic_store(P.bar, 0u, __ATOMIC_RELAXED, __HIP_MEMORY_SCOPE_AGENT);
          __hip_atomic_store(P.bar + 32, g + 1u, __ATOMIC_RELEASE, __HIP_MEMORY_SCOPE_AGENT);
        } else {
          while (__hip_atomic_load(P.bar + 32, __ATOMIC_ACQUIRE, __HIP_MEMORY_SCOPE_AGENT) == g)
            __builtin_amdgcn_s_sleep(2);
        }
        __threadfence();
      }
      __syncthreads();
    }
  }
}

// out[b] = sigmoid(h2[b,:] @ Wout + bout)
__global__ void output_kernel(const bf16* __restrict__ H2, const float* __restrict__ Wout,
                              const float* __restrict__ bout, float* __restrict__ out) {
  int w = threadIdx.x >> 6, l = threadIdx.x & 63;
  int row = blockIdx.x * 4 + w;
  const bf16* h = H2 + (size_t)row * 512;
  float s = 0.f;
#pragma unroll
  for (int k = 0; k < 8; ++k) {
    int kk = l + k * 64;
    s += __bfloat162float(h[kk]) * Wout[kk];
  }
#pragma unroll
  for (int off = 32; off > 0; off >>= 1) s += __shfl_down(s, off);
  if (l == 0) out[row] = sigf(s + bout[0]);
}

extern "C" void kernel_launch(void* const* d_in, const int* in_sizes, int n_in,
                              void* d_out, int out_size, void* d_ws, size_t ws_size,
                              hipStream_t stream) {
  const int* tokens = (const int*)d_in[0];
  const float* emb = (const float*)d_in[1];
  const float* W1 = (const float*)d_in[2];
  const float* U1 = (const float*)d_in[3];
  const float* b1 = (const float*)d_in[4];
  const float* W2 = (const float*)d_in[5];
  const float* U2 = (const float*)d_in[6];
  const float* b2 = (const float*)d_in[7];
  const float* Wout = (const float*)d_in[8];
  const float* bout = (const float*)d_in[9];
  float* out = (float*)d_out;
  char* ws = (char*)d_ws;

  const size_t oXP = 0;          // 20971520
  const size_t oW1T = 20971520;  // 524288
  const size_t oU1T = 21495808;  // 2097152
  const size_t oW2T = 23592960;  // 2097152
  const size_t oU2T = 25690112;  // 2097152
  const size_t oH1 = 27787264;   // 2097152 (2 bufs)
  const size_t oH2 = 29884416;   // 2097152
  const size_t oBar = 31981568;  // 256
  if (ws_size < 31981824) return;

  bf16* XP = (bf16*)(ws + oXP);
  bf16* W1T = (bf16*)(ws + oW1T);
  bf16* U1T = (bf16*)(ws + oU1T);
  bf16* W2T = (bf16*)(ws + oW2T);
  bf16* U2T = (bf16*)(ws + oU2T);
  bf16* H1 = (bf16*)(ws + oH1);
  bf16* H2 = (bf16*)(ws + oH2);
  unsigned* bar = (unsigned*)(ws + oBar);

  hipMemsetAsync(ws + oH1, 0, 1048576, stream);  // H1 buf0
  hipMemsetAsync(ws + oH2, 0, 1048576, stream);  // H2 buf0
  hipMemsetAsync(ws + oBar, 0, 256, stream);     // barrier state

  embed_kernel<<<40960, 256, 0, stream>>>(tokens, emb, XP);
  transpose_kernel<<<dim3(64, 4), 256, 0, stream>>>(W1, W1T, 100, 128);
  transpose_kernel<<<dim3(64, 16), 256, 0, stream>>>(U1, U1T, 512, 512);
  transpose_kernel<<<dim3(64, 16), 256, 0, stream>>>(W2, W2T, 512, 512);
  transpose_kernel<<<dim3(64, 16), 256, 0, stream>>>(U2, U2T, 512, 512);

  PP P;
  P.XP = XP; P.W1T = W1T; P.U1T = U1T; P.W2T = W2T; P.U2T = U2T;
  P.b1 = b1; P.b2 = b2; P.H1 = H1; P.H2 = H2; P.bar = bar;
  void* args[] = {&P};
  hipLaunchCooperativeKernel((const void*)lstm_persistent, dim3(512), dim3(256),
                             args, 0, stream);

  output_kernel<<<256, 256, 0, stream>>>(H2, Wout, bout, out);
}

// Round 4
// 2796.704 us; speedup vs baseline: 2.4890x; 2.4890x over previous
//
#include <hip/hip_runtime.h>
#include <hip/hip_bf16.h>
#include <stdint.h>

// 2-layer LSTM, B=1024 T=80 E=100 U=512 — persistent-weights cooperative kernel.
// R4: weights live in VGPRs for the whole run (128 B-frags/wave), activations
// staged via global_load_lds, grid barrier = tree arrivals + RELAXED spin
// (R3's acquire-spin emitted buffer_inv per poll -> L2 annihilation, 87us/phase).
// Block = 128 rows x (16 units x 4 gates); waves = 2 gate-pairs x 2 K-parities.
// c-state in registers; H bf16 ping-pong; bm<->XCD swizzle for L2 locality.

#define T_ 80

using bf16 = __hip_bfloat16;
typedef __attribute__((ext_vector_type(8))) short short8;
typedef __attribute__((ext_vector_type(4))) float f32x4;

__device__ __forceinline__ float sigf(float x) { return 1.f / (1.f + __expf(-x)); }
__device__ __forceinline__ float tanh_f(float x) { return 2.f / (1.f + __expf(-2.f * x)) - 1.f; }

typedef const __attribute__((address_space(1))) void* gp1_t;
typedef __attribute__((address_space(3))) void* lp3_t;
__device__ __forceinline__ void llds16(const void* g, void* l) {
  __builtin_amdgcn_global_load_lds((gp1_t)g, (lp3_t)l, 16, 0, 0);
}

// XP[t][b][e] (e padded to 128), bf16
__global__ void embed_kernel(const int* __restrict__ tokens, const float* __restrict__ emb,
                             bf16* __restrict__ XP) {
  int idx = blockIdx.x * 256 + threadIdx.x;
  int e = idx & 127;
  int bt = idx >> 7;
  int b = bt & 1023;
  int t = bt >> 10;
  if (t >= T_) return;
  int tok = tokens[b * T_ + t];
  float v = (e < 100) ? emb[tok * 100 + e] : 0.f;
  XP[idx] = __float2bfloat16(v);
}

// W [Kreal][2048] fp32 -> WT [2048][Kp] bf16 via LDS tile
__global__ void transpose_kernel(const float* __restrict__ W, bf16* __restrict__ WT,
                                 int Kreal, int Kp) {
  __shared__ float tile[32][33];
  int tn = blockIdx.x * 32;
  int tk = blockIdx.y * 32;
  int lx = threadIdx.x & 31;
  int ly = threadIdx.x >> 5;
#pragma unroll
  for (int r = ly; r < 32; r += 8) {
    int k = tk + r;
    tile[r][lx] = (k < Kreal) ? W[(size_t)k * 2048 + tn + lx] : 0.f;
  }
  __syncthreads();
#pragma unroll
  for (int r = ly; r < 32; r += 8)
    WT[(size_t)(tn + r) * Kp + tk + lx] = __float2bfloat16(tile[lx][r]);
}

struct PP {
  const bf16* XP;
  const bf16* W1T; const bf16* U1T; const bf16* W2T; const bf16* U2T;
  const float* b1; const float* b2;
  bf16* H1; bf16* H2;   // ping-pong pairs, stride 524288 elems
  unsigned* bar;        // [g*16]=group counters g<8, [128]=root, [144]=generation
};

// Tree barrier: 8 groups x 64 arrivals -> root x 8. RELAXED spins (agent-relaxed
// atomic loads are sc1/L2-bypass: coherent, no buffer_inv). One acquire at exit.
__device__ __forceinline__ void grid_barrier(unsigned* bar, int bid, int tid) {
  __syncthreads();  // drains vmcnt: all H stores at least in L2
  if (tid == 0) {
    __builtin_amdgcn_fence(__ATOMIC_RELEASE, "agent");  // wbL2: push H to coherence point
    unsigned* grp = bar + (bid & 7) * 16;
    unsigned* root = bar + 128;
    unsigned* gen = bar + 144;
    unsigned g = __hip_atomic_load(gen, __ATOMIC_RELAXED, __HIP_MEMORY_SCOPE_AGENT);
    unsigned a = __hip_atomic_fetch_add(grp, 1u, __ATOMIC_RELAXED, __HIP_MEMORY_SCOPE_AGENT);
    if (a == 63u) {
      __hip_atomic_store(grp, 0u, __ATOMIC_RELAXED, __HIP_MEMORY_SCOPE_AGENT);
      unsigned r = __hip_atomic_fetch_add(root, 1u, __ATOMIC_RELAXED, __HIP_MEMORY_SCOPE_AGENT);
      if (r == 7u) {
        __hip_atomic_store(root, 0u, __ATOMIC_RELAXED, __HIP_MEMORY_SCOPE_AGENT);
        __hip_atomic_store(gen, g + 1u, __ATOMIC_RELEASE, __HIP_MEMORY_SCOPE_AGENT);
      }
    }
    while (__hip_atomic_load(gen, __ATOMIC_RELAXED, __HIP_MEMORY_SCOPE_AGENT) == g)
      __builtin_amdgcn_s_sleep(4);
    __builtin_amdgcn_fence(__ATOMIC_ACQUIRE, "agent");  // single invL2, once per phase
  }
  __syncthreads();
}

// L1: z = [XP_t | H1] @ [W1;U1]; L2: z = [H1_new | H2] @ [W2;U2].
// Wave (ch,kh): 128 rows x 32 cols (gates 2ch,2ch+1 x 16 units), K-chunks == kh (mod 2).
template <bool L1>
__device__ void lstm_run(const PP& P, char* smem, int bid) {
  constexpr int NC0 = L1 ? 4 : 16;     // chunks from src0
  constexpr int NK = L1 ? 20 : 32;     // total 32-K chunks
  constexpr int NS = NK / 2;           // slots (2 chunks each)
  constexpr int LD0 = L1 ? 128 : 512;
  const int tid = threadIdx.x;
  const int w = tid >> 6, l = tid & 63, q = l >> 4, m = l & 15;
  const int ch = w & 1, kh = w >> 1;
  const int bm = bid & 7;              // == XCD (heuristic locality, not correctness)
  const int ug = (bid >> 3) & 31;

  const bf16* Wt = L1 ? P.W1T : P.W2T;
  const bf16* Ut = L1 ? P.U1T : P.U2T;
  const float* bias = L1 ? P.b1 : P.b2;
  bf16* Hpair = L1 ? P.H1 : P.H2;
  const bf16* S0 = L1 ? P.XP : P.H1;

  // persistent B-fragments: BF[slot][ct], gate g=ch*2+ct, chunk c=2*slot+kh
  short8 BF[NS][2];
#pragma unroll
  for (int s = 0; s < NS; ++s) {
    int c = 2 * s + kh;
#pragma unroll
    for (int ct = 0; ct < 2; ++ct) {
      int nr = (ch * 2 + ct) * 512 + ug * 16 + m;
      const bf16* src = (c < NC0) ? (Wt + (size_t)nr * LD0 + c * 32)
                                  : (Ut + (size_t)nr * 512 + (c - NC0) * 32);
      BF[s][ct] = *(const short8*)(src + q * 8);
    }
  }

  float creg[8] = {0, 0, 0, 0, 0, 0, 0, 0};
  float* zs = (float*)(smem + 32768);
  const int uu = tid & 15, rb = tid >> 4;

  for (int phase = 0; phase <= T_; ++phase) {
    const int t = L1 ? phase : phase - 1;
    const bool active = L1 ? (phase < T_) : (phase >= 1);
    if (active) {
      const bf16* A0 = L1 ? (S0 + (size_t)t * 131072)
                          : (S0 + (size_t)((t + 1) & 1) * 524288);
      const bf16* A1 = Hpair + (size_t)(t & 1) * 524288;
      bf16* Ho = Hpair + (size_t)((t + 1) & 1) * 524288;

      f32x4 acc[8][2];
#pragma unroll
      for (int rt = 0; rt < 8; ++rt) {
        acc[rt][0] = f32x4{0.f, 0.f, 0.f, 0.f};
        acc[rt][1] = f32x4{0.f, 0.f, 0.f, 0.f};
      }

      // stage slot s (chunks 2s, 2s+1): LDS chunk layout [koct 0..3][row 0..127] x16B
      auto stage = [&](int s) {
#pragma unroll
        for (int cc = 0; cc < 2; ++cc) {
          int c = 2 * s + cc;
          const bf16* src;
          int ld, k0;
          if (c < NC0) { src = A0; ld = LD0; k0 = c * 32; }
          else { src = A1; ld = 512; k0 = (c - NC0) * 32; }
          char* cb = smem + (s & 1) * 16384 + cc * 8192;
#pragma unroll
          for (int i = 0; i < 2; ++i) {
            int u2 = i * 4 + w;            // wave-uniform 0..7
            int koct = u2 >> 1;
            int rowb = (u2 & 1) * 64;
            llds16(src + (size_t)(bm * 128 + rowb + l) * ld + k0 + koct * 8,
                   cb + u2 * 1024);
          }
        }
      };

      stage(0);
#pragma unroll
      for (int s = 0; s < NS; ++s) {
        __syncthreads();
        if (s + 1 < NS) stage(s + 1);
        const char* cb = smem + (s & 1) * 16384 + kh * 8192;
#pragma unroll
        for (int rt = 0; rt < 8; ++rt) {
          short8 af = *(const short8*)(cb + q * 2048 + (rt * 16 + m) * 16);
          acc[rt][0] = __builtin_amdgcn_mfma_f32_16x16x32_bf16(af, BF[s][0], acc[rt][0], 0, 0, 0);
          acc[rt][1] = __builtin_amdgcn_mfma_f32_16x16x32_bf16(af, BF[s][1], acc[rt][1], 0, 0, 0);
        }
      }

      // K-parity combine in zs[128][64], then in-block gate epilogue
      __syncthreads();
      if (kh == 0) {
#pragma unroll
        for (int rt = 0; rt < 8; ++rt)
#pragma unroll
          for (int ct = 0; ct < 2; ++ct)
#pragma unroll
            for (int r = 0; r < 4; ++r)
              zs[(rt * 16 + q * 4 + r) * 64 + ch * 32 + ct * 16 + m] = acc[rt][ct][r];
      }
      __syncthreads();
      if (kh == 1) {
#pragma unroll
        for (int rt = 0; rt < 8; ++rt)
#pragma unroll
          for (int ct = 0; ct < 2; ++ct)
#pragma unroll
            for (int r = 0; r < 4; ++r)
              zs[(rt * 16 + q * 4 + r) * 64 + ch * 32 + ct * 16 + m] += acc[rt][ct][r];
      }
      __syncthreads();

      const float bi = bias[0 * 512 + ug * 16 + uu];
      const float bff = bias[1 * 512 + ug * 16 + uu];
      const float bgg = bias[2 * 512 + ug * 16 + uu];
      const float boo = bias[3 * 512 + ug * 16 + uu];
#pragma unroll
      for (int p = 0; p < 8; ++p) {
        int row = rb + p * 16;
        float zi = zs[row * 64 + 0 + uu] + bi;
        float zf = zs[row * 64 + 16 + uu] + bff;
        float zg = zs[row * 64 + 32 + uu] + bgg;
        float zo = zs[row * 64 + 48 + uu] + boo;
        float c = sigf(zf) * creg[p] + sigf(zi) * tanh_f(zg);
        creg[p] = c;
        Ho[(size_t)(bm * 128 + row) * 512 + ug * 16 + uu] = __float2bfloat16(sigf(zo) * tanh_f(c));
      }
    }
    if (phase < T_) grid_barrier(P.bar, bid, tid);
  }
}

__global__ __launch_bounds__(256, 2) void lstm_persistent(PP P) {
  __shared__ alignas(16) char smem[65536];  // 32KB staging (2 slots x 16KB) + 32KB zs
  const int bid = blockIdx.x;
  if (bid < 256) lstm_run<true>(P, smem, bid);
  else lstm_run<false>(P, smem, bid);
}

// out[b] = sigmoid(h2[b,:] @ Wout + bout)
__global__ void output_kernel(const bf16* __restrict__ H2, const float* __restrict__ Wout,
                              const float* __restrict__ bout, float* __restrict__ out) {
  int w = threadIdx.x >> 6, l = threadIdx.x & 63;
  int row = blockIdx.x * 4 + w;
  const bf16* h = H2 + (size_t)row * 512;
  float s = 0.f;
#pragma unroll
  for (int k = 0; k < 8; ++k) {
    int kk = l + k * 64;
    s += __bfloat162float(h[kk]) * Wout[kk];
  }
#pragma unroll
  for (int off = 32; off > 0; off >>= 1) s += __shfl_down(s, off);
  if (l == 0) out[row] = sigf(s + bout[0]);
}

extern "C" void kernel_launch(void* const* d_in, const int* in_sizes, int n_in,
                              void* d_out, int out_size, void* d_ws, size_t ws_size,
                              hipStream_t stream) {
  const int* tokens = (const int*)d_in[0];
  const float* emb = (const float*)d_in[1];
  const float* W1 = (const float*)d_in[2];
  const float* U1 = (const float*)d_in[3];
  const float* b1 = (const float*)d_in[4];
  const float* W2 = (const float*)d_in[5];
  const float* U2 = (const float*)d_in[6];
  const float* b2 = (const float*)d_in[7];
  const float* Wout = (const float*)d_in[8];
  const float* bout = (const float*)d_in[9];
  float* out = (float*)d_out;
  char* ws = (char*)d_ws;

  const size_t oXP = 0;          // 20971520
  const size_t oW1T = 20971520;  // 524288
  const size_t oU1T = 21495808;  // 2097152
  const size_t oW2T = 23592960;  // 2097152
  const size_t oU2T = 25690112;  // 2097152
  const size_t oH1 = 27787264;   // 2097152 (2 bufs)
  const size_t oH2 = 29884416;   // 2097152
  const size_t oBar = 31981568;  // 1024
  if (ws_size < 31982592) return;

  bf16* XP = (bf16*)(ws + oXP);
  bf16* W1T = (bf16*)(ws + oW1T);
  bf16* U1T = (bf16*)(ws + oU1T);
  bf16* W2T = (bf16*)(ws + oW2T);
  bf16* U2T = (bf16*)(ws + oU2T);
  bf16* H1 = (bf16*)(ws + oH1);
  bf16* H2 = (bf16*)(ws + oH2);
  unsigned* bar = (unsigned*)(ws + oBar);

  hipMemsetAsync(ws + oH1, 0, 1048576, stream);  // H1 buf0
  hipMemsetAsync(ws + oH2, 0, 1048576, stream);  // H2 buf0
  hipMemsetAsync(ws + oBar, 0, 1024, stream);    // barrier state

  embed_kernel<<<40960, 256, 0, stream>>>(tokens, emb, XP);
  transpose_kernel<<<dim3(64, 4), 256, 0, stream>>>(W1, W1T, 100, 128);
  transpose_kernel<<<dim3(64, 16), 256, 0, stream>>>(U1, U1T, 512, 512);
  transpose_kernel<<<dim3(64, 16), 256, 0, stream>>>(W2, W2T, 512, 512);
  transpose_kernel<<<dim3(64, 16), 256, 0, stream>>>(U2, U2T, 512, 512);

  PP P;
  P.XP = XP; P.W1T = W1T; P.U1T = U1T; P.W2T = W2T; P.U2T = U2T;
  P.b1 = b1; P.b2 = b2; P.H1 = H1; P.H2 = H2; P.bar = bar;
  void* args[] = {&P};
  hipLaunchCooperativeKernel((const void*)lstm_persistent, dim3(512), dim3(256),
                             args, 0, stream);

  output_kernel<<<256, 256, 0, stream>>>(H2, Wout, bout, out);
}